// Round 1
// baseline (1820.638 us; speedup 1.0000x reference)
//
#include <hip/hip_runtime.h>
#include <hip/hip_bf16.h>
#include <math.h>

// Problem constants (fixed by setup_inputs): N=50000, E=800000, D=64, K=500, C=64
#define DD 64          // feature dim of x
#define KK 500         // assign clusters
#define KK4 125        // K/4 (float4 per S/Q row)

// ---------------- degree histogram ----------------
__global__ void hist_kernel(const int* __restrict__ rowv, const int* __restrict__ colv,
                            int* __restrict__ cnt_row, int* __restrict__ cnt_col, int E) {
    int e = blockIdx.x * blockDim.x + threadIdx.x;
    if (e >= E) return;
    atomicAdd(&cnt_row[rowv[e]], 1);
    atomicAdd(&cnt_col[colv[e]], 1);
}

__global__ void dinv_kernel(const int* __restrict__ cnt_row, float* __restrict__ dinv, int n) {
    int i = blockIdx.x * blockDim.x + threadIdx.x;
    if (i >= n) return;
    float deg = (float)(cnt_row[i] + 1);   // +1 self loop; deg counted over `row` (source)
    dinv[i] = 1.0f / sqrtf(deg);
}

// ---------------- exclusive scan (single block per array; grid.x==2) ----------------
__global__ void scan2_kernel(const int* __restrict__ cntA, int* __restrict__ offsA, int* __restrict__ curA,
                             const int* __restrict__ cntB, int* __restrict__ offsB, int* __restrict__ curB,
                             int n) {
    const int* cnt = blockIdx.x ? cntB : cntA;
    int* offs      = blockIdx.x ? offsB : offsA;
    int* cur       = blockIdx.x ? curB  : curA;
    __shared__ int sums[1024];
    int t = threadIdx.x;
    int chunk = (n + 1023) / 1024;
    int begin = min(t * chunk, n);
    int end   = min(begin + chunk, n);
    int s = 0;
    for (int i = begin; i < end; ++i) s += cnt[i];
    sums[t] = s;
    __syncthreads();
    for (int off = 1; off < 1024; off <<= 1) {
        int v = (t >= off) ? sums[t - off] : 0;
        __syncthreads();
        sums[t] += v;
        __syncthreads();
    }
    int run = (t == 0) ? 0 : sums[t - 1];
    for (int i = begin; i < end; ++i) {
        offs[i] = run; cur[i] = run; run += cnt[i];
    }
    if (t == 1023) offs[n] = sums[1023];
}

// ---------------- CSR placement (counting sort) ----------------
__global__ void place_kernel(const int* __restrict__ rowv, const int* __restrict__ colv,
                             int* __restrict__ cur_col, int* __restrict__ cur_row,
                             int* __restrict__ esrc, int* __restrict__ edst, int E) {
    int e = blockIdx.x * blockDim.x + threadIdx.x;
    if (e >= E) return;
    int r = rowv[e], c = colv[e];
    int p = atomicAdd(&cur_col[c], 1); esrc[p] = r;   // in-edge list of c (sources)
    int q = atomicAdd(&cur_row[r], 1); edst[q] = c;   // out-edge list of r (targets)
}

// ---------------- out = dinv * (x @ W + b); block: 32 rows x 64 cols ----------------
__global__ void gemm_xw_kernel(const float* __restrict__ x, const float* __restrict__ W,
                               const float* __restrict__ bias, const float* __restrict__ dinv,
                               float* __restrict__ out, int n, int C) {
    const int C4 = C >> 2;
    int r0 = blockIdx.x * 32;
    int cb = blockIdx.y;
    __shared__ float xs[32 * 68];   // 64-col x tile, row stride 68 (bank-conflict pad)
    int t = threadIdx.x;
#pragma unroll
    for (int k = 0; k < 2; ++k) {
        int idx = t * 2 + k;
        int rr = idx >> 4, c4 = idx & 15;
        int row = r0 + rr;
        float4 v = make_float4(0.f, 0.f, 0.f, 0.f);
        if (row < n) v = ((const float4*)x)[(size_t)row * 16 + c4];
        *(float4*)&xs[rr * 68 + c4 * 4] = v;
    }
    __syncthreads();
    int lr = t >> 3;       // 0..31 local row
    int cg = t & 7;        // 0..7 col group
    int f40 = cb * 16 + cg * 2;
    int f41 = f40 + 1;
    bool w0 = f40 < C4, w1 = f41 < C4;
    float4 acc0 = make_float4(0.f,0.f,0.f,0.f), acc1 = make_float4(0.f,0.f,0.f,0.f);
    const float4* W4 = (const float4*)W;
    for (int d = 0; d < 64; ++d) {
        float xv = xs[lr * 68 + d];
        if (w0) { float4 w = W4[(size_t)d * C4 + f40];
                  acc0.x += xv*w.x; acc0.y += xv*w.y; acc0.z += xv*w.z; acc0.w += xv*w.w; }
        if (w1) { float4 w = W4[(size_t)d * C4 + f41];
                  acc1.x += xv*w.x; acc1.y += xv*w.y; acc1.z += xv*w.z; acc1.w += xv*w.w; }
    }
    int row = r0 + lr;
    if (row < n) {
        float di = dinv[row];
        const float4* b4 = (const float4*)bias;
        float4* o4 = (float4*)out;
        if (w0) { float4 bv = b4[f40];
                  float4 r = make_float4(di*(acc0.x+bv.x), di*(acc0.y+bv.y),
                                         di*(acc0.z+bv.z), di*(acc0.w+bv.w));
                  o4[(size_t)row * C4 + f40] = r; }
        if (w1) { float4 bv = b4[f41];
                  float4 r = make_float4(di*(acc1.x+bv.x), di*(acc1.y+bv.y),
                                         di*(acc1.z+bv.z), di*(acc1.w+bv.w));
                  o4[(size_t)row * C4 + f41] = r; }
    }
}

// ---------------- Z[i] = dinv[i]*(P[i] + sum_{in-edges} P[src]); one wave/node ----------------
__global__ void zagg_kernel(const float* __restrict__ P, const int* __restrict__ offs,
                            const int* __restrict__ esrc, const float* __restrict__ dinv,
                            float* __restrict__ Z, int n) {
    int wv = (blockIdx.x * blockDim.x + threadIdx.x) >> 6;
    int lane = threadIdx.x & 63;
    if (wv >= n) return;
    float acc = P[(size_t)wv * 64 + lane];
    int pend = offs[wv + 1];
    for (int p = offs[wv]; p < pend; ++p) {
        int s = esrc[p];
        acc += P[(size_t)s * 64 + lane];
    }
    Z[(size_t)wv * 64 + lane] = dinv[wv] * acc;
}

// ---------------- fused: Lacc aggregate + scale + row softmax -> S; one wave/node ----------------
__global__ void softmax_agg_kernel(const float* __restrict__ Q, const int* __restrict__ offs,
                                   const int* __restrict__ esrc, const float* __restrict__ dinv,
                                   float* __restrict__ S, int n) {
    int wv = (blockIdx.x * blockDim.x + threadIdx.x) >> 6;
    int lane = threadIdx.x & 63;
    if (wv >= n) return;
    const float4* Q4 = (const float4*)Q;
    int i0 = lane;          // < 125 always
    int i1 = lane + 64;
    bool v1 = (i1 < KK4);
    float4 a0 = Q4[(size_t)wv * KK4 + i0];
    float4 a1 = v1 ? Q4[(size_t)wv * KK4 + i1] : make_float4(0.f,0.f,0.f,0.f);
    int pend = offs[wv + 1];
    for (int p = offs[wv]; p < pend; ++p) {
        int s = esrc[p];
        const float4* r = Q4 + (size_t)s * KK4;
        float4 q0 = r[i0];
        a0.x += q0.x; a0.y += q0.y; a0.z += q0.z; a0.w += q0.w;
        if (v1) { float4 q1 = r[i1];
                  a1.x += q1.x; a1.y += q1.y; a1.z += q1.z; a1.w += q1.w; }
    }
    float di = dinv[wv];
    a0.x *= di; a0.y *= di; a0.z *= di; a0.w *= di;
    a1.x *= di; a1.y *= di; a1.z *= di; a1.w *= di;
    // row max
    float m = fmaxf(fmaxf(a0.x, a0.y), fmaxf(a0.z, a0.w));
    if (v1) m = fmaxf(m, fmaxf(fmaxf(a1.x, a1.y), fmaxf(a1.z, a1.w)));
#pragma unroll
    for (int o = 32; o > 0; o >>= 1) m = fmaxf(m, __shfl_xor(m, o, 64));
    // exp + sum
    float4 e0 = make_float4(expf(a0.x - m), expf(a0.y - m), expf(a0.z - m), expf(a0.w - m));
    float4 e1 = make_float4(0.f,0.f,0.f,0.f);
    float ssum = e0.x + e0.y + e0.z + e0.w;
    if (v1) {
        e1 = make_float4(expf(a1.x - m), expf(a1.y - m), expf(a1.z - m), expf(a1.w - m));
        ssum += e1.x + e1.y + e1.z + e1.w;
    }
#pragma unroll
    for (int o = 32; o > 0; o >>= 1) ssum += __shfl_xor(ssum, o, 64);
    float rs = 1.0f / ssum;
    float4* S4 = (float4*)S;
    S4[(size_t)wv * KK4 + i0] = make_float4(e0.x*rs, e0.y*rs, e0.z*rs, e0.w*rs);
    if (v1) S4[(size_t)wv * KK4 + i1] = make_float4(e1.x*rs, e1.y*rs, e1.z*rs, e1.w*rs);
}

// ---------------- AS[r] = sum_{out-edges of r} S[dst]; one wave/node ----------------
__global__ void as_agg_kernel(const float* __restrict__ S, const int* __restrict__ offs,
                              const int* __restrict__ edst, float* __restrict__ AS, int n) {
    int wv = (blockIdx.x * blockDim.x + threadIdx.x) >> 6;
    int lane = threadIdx.x & 63;
    if (wv >= n) return;
    const float4* S4 = (const float4*)S;
    int i0 = lane;
    int i1 = lane + 64;
    bool v1 = (i1 < KK4);
    float4 a0 = make_float4(0.f,0.f,0.f,0.f), a1 = make_float4(0.f,0.f,0.f,0.f);
    int pend = offs[wv + 1];
    for (int p = offs[wv]; p < pend; ++p) {
        int c = edst[p];
        const float4* r = S4 + (size_t)c * KK4;
        float4 q0 = r[i0];
        a0.x += q0.x; a0.y += q0.y; a0.z += q0.z; a0.w += q0.w;
        if (v1) { float4 q1 = r[i1];
                  a1.x += q1.x; a1.y += q1.y; a1.z += q1.z; a1.w += q1.w; }
    }
    float4* O4 = (float4*)AS;
    O4[(size_t)wv * KK4 + i0] = a0;
    if (v1) O4[(size_t)wv * KK4 + i1] = a1;
}

// ---------------- out[a,b] += sum_n X[n,a]*Y[n,b]; 64x64 tile, split-N, atomic epilogue ----------
__global__ void gemm_tn_kernel(const float* __restrict__ X, const float* __restrict__ Y,
                               float* __restrict__ out, int n, int KA, int KB, int nPerBlock) {
    const int a0 = blockIdx.x * 64;
    const int b0 = blockIdx.y * 64;
    const int nbeg = blockIdx.z * nPerBlock;
    const int nend = min(nbeg + nPerBlock, n);
    __shared__ float Xs[8 * 64];
    __shared__ float Ys[8 * 64];
    const int t = threadIdx.x;
    const int tx = t & 15, ty = t >> 4;
    float acc[4][4] = {};
    const int KA4 = KA >> 2, KB4 = KB >> 2;
    const int a04 = a0 >> 2, b04 = b0 >> 2;
    for (int nb = nbeg; nb < nend; nb += 8) {
        __syncthreads();
        {
            int which = t >> 7;       // 0: X, 1: Y
            int lt = t & 127;
            int nr = lt >> 4;         // 0..7
            int f4 = lt & 15;         // 0..15
            int nn = nb + nr;
            float4 v = make_float4(0.f,0.f,0.f,0.f);
            if (nn < nend) {
                if (which == 0) { if (a04 + f4 < KA4) v = ((const float4*)X)[(size_t)nn * KA4 + a04 + f4]; }
                else            { if (b04 + f4 < KB4) v = ((const float4*)Y)[(size_t)nn * KB4 + b04 + f4]; }
            }
            float* dst = which ? Ys : Xs;
            ((float4*)dst)[nr * 16 + f4] = v;
        }
        __syncthreads();
#pragma unroll
        for (int kk = 0; kk < 8; ++kk) {
            float xa[4], yb[4];
#pragma unroll
            for (int i = 0; i < 4; ++i) xa[i] = Xs[kk * 64 + tx * 4 + i];
#pragma unroll
            for (int j = 0; j < 4; ++j) yb[j] = Ys[kk * 64 + ty * 4 + j];
#pragma unroll
            for (int i = 0; i < 4; ++i)
#pragma unroll
                for (int j = 0; j < 4; ++j)
                    acc[i][j] += xa[i] * yb[j];
        }
    }
#pragma unroll
    for (int i = 0; i < 4; ++i) {
        int a = a0 + tx * 4 + i;
        if (a < KA) {
#pragma unroll
            for (int j = 0; j < 4; ++j) {
                int b = b0 + ty * 4 + j;
                if (b < KB) atomicAdd(&out[(size_t)a * KB + b], acc[i][j]);
            }
        }
    }
}

extern "C" void kernel_launch(void* const* d_in, const int* in_sizes, int n_in,
                              void* d_out, int out_size, void* d_ws, size_t ws_size,
                              hipStream_t stream) {
    const float* x        = (const float*)d_in[0];
    const int*   ei       = (const int*)d_in[1];
    const float* W_embed  = (const float*)d_in[2];
    const float* b_embed  = (const float*)d_in[3];
    const float* W_assign = (const float*)d_in[4];
    const float* b_assign = (const float*)d_in[5];

    const int N = in_sizes[0] / DD;     // 50000
    const int E = in_sizes[1] / 2;      // 800000
    const int C = in_sizes[3];          // 64
    const int K = in_sizes[5];          // 500

    const int* rowv = ei;               // sources
    const int* colv = ei + E;           // targets

    // workspace layout (256B aligned)
    char* p = (char*)d_ws;
    auto alloc = [&](size_t bytes) -> void* {
        void* r = (void*)p;
        p += (bytes + 255) & ~(size_t)255;
        return r;
    };
    int*   cnt_col  = (int*)alloc((size_t)N * 4);
    int*   cnt_row  = (int*)alloc((size_t)N * 4);
    int*   offs_col = (int*)alloc((size_t)(N + 1) * 4);
    int*   offs_row = (int*)alloc((size_t)(N + 1) * 4);
    int*   cur_col  = (int*)alloc((size_t)N * 4);
    int*   cur_row  = (int*)alloc((size_t)N * 4);
    float* dinv     = (float*)alloc((size_t)N * 4);
    int*   esrc     = (int*)alloc((size_t)E * 4);
    int*   edst     = (int*)alloc((size_t)E * 4);
    float* P        = (float*)alloc((size_t)N * DD * 4);   // dinv-scaled embed features
    float* Z        = (float*)alloc((size_t)N * DD * 4);   // GCN embed output
    float* Q        = (float*)alloc((size_t)N * KK * 4);   // dinv-scaled assign features; reused as AS
    float* S        = (float*)alloc((size_t)N * KK * 4);   // softmax assignments

    float* outX = (float*)d_out;            // [K, C]
    float* outA = outX + (size_t)K * C;     // [K, K]

    // 1. zero counters + output (ws/out are poisoned 0xAA each launch)
    hipMemsetAsync(cnt_col, 0, (size_t)N * 4, stream);
    hipMemsetAsync(cnt_row, 0, (size_t)N * 4, stream);
    hipMemsetAsync(d_out, 0, (size_t)out_size * 4, stream);

    // 2. degree histograms
    hist_kernel<<<(E + 255) / 256, 256, 0, stream>>>(rowv, colv, cnt_row, cnt_col, E);

    // 3. dinv = (1 + outdeg)^-1/2
    dinv_kernel<<<(N + 255) / 256, 256, 0, stream>>>(cnt_row, dinv, N);

    // 4. CSR offsets (both directions in one launch, 2 blocks)
    scan2_kernel<<<2, 1024, 0, stream>>>(cnt_col, offs_col, cur_col,
                                         cnt_row, offs_row, cur_row, N);

    // 5. CSR placement
    place_kernel<<<(E + 255) / 256, 256, 0, stream>>>(rowv, colv, cur_col, cur_row, esrc, edst, E);

    // 6. P = dinv * (x @ W_embed + b_embed)
    {
        dim3 g((N + 31) / 32, 1);
        gemm_xw_kernel<<<g, 256, 0, stream>>>(x, W_embed, b_embed, dinv, P, N, C);
    }
    // 7. Z aggregation (GCN embed output)
    zagg_kernel<<<(N + 3) / 4, 256, 0, stream>>>(P, offs_col, esrc, dinv, Z, N);

    // 8. Q = dinv * (x @ W_assign + b_assign)
    {
        dim3 g((N + 31) / 32, (K + 63) / 64);
        gemm_xw_kernel<<<g, 256, 0, stream>>>(x, W_assign, b_assign, dinv, Q, N, K);
    }
    // 9. fused aggregate + softmax -> S
    softmax_agg_kernel<<<(N + 3) / 4, 256, 0, stream>>>(Q, offs_col, esrc, dinv, S, N);

    // 10. AS = A @ S (original edges only), reuse Q buffer
    float* AS = Q;
    as_agg_kernel<<<(N + 3) / 4, 256, 0, stream>>>(S, offs_row, edst, AS, N);

    // 11. next_X = S^T @ Z
    {
        int nPer = 512;
        dim3 g((K + 63) / 64, (C + 63) / 64, (N + nPer - 1) / nPer);
        gemm_tn_kernel<<<g, 256, 0, stream>>>(S, Z, outX, N, K, C, nPer);
    }
    // 12. next_A = S^T @ AS
    {
        int nPer = 2048;
        dim3 g((K + 63) / 64, (K + 63) / 64, (N + nPer - 1) / nPer);
        gemm_tn_kernel<<<g, 256, 0, stream>>>(S, AS, outA, N, K, K, nPer);
    }
}